// Round 16
// baseline (272.346 us; speedup 1.0000x reference)
//
#include <hip/hip_runtime.h>
#include <hip/hip_bf16.h>

// Problem constants
#define N_ROWS   16384      // 8*2048
#define EMB_DIM  64
#define NUM_EMB  8192
#define TOP_K    10
#define PERP_W   0.01

// Pass-1 (unchanged from r14/r15, absmax 0.0): grid (1024, 2); block = 256 thr
// = 4 waves = 16 rows x 4096 codes. Swizzled bf16 codebook -> fully coalesced
// A-loads. Per-lane register top-12 (packed u32 key), ballot key-top-16 per
// row per half -> 32 candidates/row. fp64 re-rank restores exact (d,idx).
#define M_CHUNK   12

// Output layout (all float32, concatenated in return order)
#define QST_OFF   0
#define LOSS_OFF  (N_ROWS * EMB_DIM)                 // 1048576
#define IDX_OFF   (LOSS_OFF + 1)                     // 1048577
#define MIND_OFF  (IDX_OFF + N_ROWS)                 // 1064961
#define PERP_OFF  (MIND_OFF + N_ROWS)                // 1081345

// ws layout (bytes)
#define WS_E2C    0                                  // 8192 f32 = 512-||e||^2/2 (32 KB)
#define WS_E2D    32768                              // 8192 f64   (64 KB)
#define WS_CBS    98304                              // swizzled bf16 codebook (1 MB)
#define WS_HIST   1146880                            // 8192 i32  (32 KB)
#define WS_LP64   1179648                            // 64 slots x 8 f64 (line-padded, 4 KB)
#define WS_NV64   1183744                            // 64 slots x 16 i32 (line-padded, 4 KB)
#define WS_DONE   1187840                            // 1 int (64 B pad)
#define WS_C32    1187904                            // 16384*32 u16 (1 MB)

typedef short bf16x8 __attribute__((ext_vector_type(8)));
typedef float f32x4  __attribute__((ext_vector_type(4)));

__device__ __forceinline__ unsigned umx(unsigned a, unsigned b) {
    return __builtin_elementwise_max(a, b);
}
__device__ __forceinline__ unsigned umn(unsigned a, unsigned b) {
    return __builtin_elementwise_min(a, b);
}

__device__ __forceinline__ unsigned short f2bf(float f) {
    // round-to-nearest-even fp32 -> bf16 (inputs are finite gaussians)
    unsigned int u = __float_as_uint(f);
    unsigned int r = u + 0x7fffu + ((u >> 16) & 1u);
    return (unsigned short)(r >> 16);
}

// ---------------------------------------------------------------------------
// Kernel 0: prep — 4 threads per code (128 blocks): quad shuffle-reduce for
// ||e||^2 (fp32 + fp64), bf16 swizzled stores (byte-identical layout to r15),
// zero histogram / staging / done-counter.
// ---------------------------------------------------------------------------
__global__ __launch_bounds__(256) void vq_prep(const float* __restrict__ cb,
                                               float* __restrict__ e2c,
                                               double* __restrict__ e2d,
                                               unsigned short* __restrict__ cbs,
                                               int* __restrict__ hist,
                                               double* __restrict__ lp64,
                                               int* __restrict__ nv64,
                                               int* __restrict__ done) {
    const int g  = blockIdx.x * 256 + threadIdx.x;   // 0..32767
    const int k  = g >> 2;                           // code 0..8191
    const int lq = g & 3;                            // dim quarter

    if (g < NUM_EMB) hist[g] = 0;
    if (g < 64) { lp64[g * 8] = 0.0; nv64[g * 16] = 0; }
    if (g == 0) *done = 0;

    const float4* rp = (const float4*)(cb + (size_t)k * EMB_DIM + lq * 16);
    float  s  = 0.0f;
    double sd = 0.0;
    unsigned pk[8];
#pragma unroll
    for (int i = 0; i < 4; ++i) {
        const float4 v = rp[i];
        s  += v.x * v.x + v.y * v.y + v.z * v.z + v.w * v.w;
        sd += (double)v.x * (double)v.x + (double)v.y * (double)v.y
            + (double)v.z * (double)v.z + (double)v.w * (double)v.w;
        pk[2 * i + 0] = (unsigned)f2bf(v.x) | ((unsigned)f2bf(v.y) << 16);
        pk[2 * i + 1] = (unsigned)f2bf(v.z) | ((unsigned)f2bf(v.w) << 16);
    }
    // quad reduce (xor 1,2 stays inside the quad)
    s  += __shfl_xor(s, 1);  s  += __shfl_xor(s, 2);
    sd += __shfl_xor(sd, 1); sd += __shfl_xor(sd, 2);
    if (lq == 0) { e2c[k] = 512.0f - 0.5f * s; e2d[k] = sd; }

    // swizzled store: this thread owns 2 of the code's 8 16B chunks
    const int tp = k >> 5, r32 = k & 31, rsub = r32 & 15;
    unsigned short* basep = cbs + ((size_t)tp << 11)
                          + ((unsigned)(r32 & 16) << 6)
                          + (rsub << 3);
    const int hi  = lq >> 1;          // 0 = lo half (dims 0..31), 1 = hi half
    const int q2s = (lq & 1) * 2;     // starting q2 within half
    uint4 c0, c1;
    c0.x = pk[0]; c0.y = pk[1]; c0.z = pk[2]; c0.w = pk[3];
    c1.x = pk[4]; c1.y = pk[5]; c1.z = pk[6]; c1.w = pk[7];
    *(uint4*)(basep + hi * 512 + (q2s + 0) * 128) = c0;
    *(uint4*)(basep + hi * 512 + (q2s + 1) * 128) = c1;
}

// ---------------------------------------------------------------------------
// Kernel 1: MFMA distance GEMM + per-lane register top-12 + per-half per-row
// key-top-16 via ballot binary search. (byte-identical to r15, 90 us)
// ---------------------------------------------------------------------------
__global__ __launch_bounds__(256) void vq_gemm_topk(
        const float* __restrict__ inp, const unsigned short* __restrict__ cbs,
        const float* __restrict__ e2c, unsigned short* __restrict__ cand32) {
    __shared__ unsigned keysh[16][193];   // [row][slot 0..191], pad 193

    const int tid   = threadIdx.x;
    const int w     = tid >> 6;        // wave chunk 0..3
    const int lane  = tid & 63;
    const int q     = lane >> 4;       // quad: k-slice for A/B, code subgroup for D
    const int rsub  = lane & 15;
    const int row0  = blockIdx.x * 16;
    const int row   = row0 + rsub;
    const int half0 = blockIdx.y * 4096;
    const int cbase = half0 + w * 1024;
    const int tpbase = cbase >> 5;     // tile-pair base index

    const int eoff = q << 2;           // e2 lane offset (floats)

    // B fragments (this lane's row, k = q*8+j and +32), fp32 -> bf16
    bf16x8 b0, b1;
    {
        const float* xp = inp + (size_t)row * EMB_DIM + q * 8;
#pragma unroll
        for (int j = 0; j < 8; ++j) b0[j] = (short)f2bf(xp[j]);
#pragma unroll
        for (int j = 0; j < 8; ++j) b1[j] = (short)f2bf(xp[32 + j]);
    }

    // sorted-desc register list of packed (score|idx8); l0 best, l11 worst
    unsigned l0=0,l1=0,l2=0,l3=0,l4=0,l5=0,l6=0,l7=0,l8=0,l9=0,l10=0,l11=0;

    // fully-coalesced loads: base is wave-uniform, lane offset = lane*16B
#define LOADP(P0,P1,P2,P3,E0,E1,TT) { \
        const bf16x8* bp_ = ((const bf16x8*)cbs) + (size_t)(tpbase + (TT)) * 256; \
        P0 = bp_[lane];        P1 = bp_[lane + 64]; \
        P2 = bp_[lane + 128];  P3 = bp_[lane + 192]; \
        const float* ep_ = e2c + cbase + (TT) * 32; \
        E0 = *(const f32x4*)(ep_ + eoff); \
        E1 = *(const f32x4*)(ep_ + eoff + 16); }

    bf16x8 A00, A01, A10, A11, B00, B01, B10, B11;
    f32x4  Ae0, Ae1, Be0, Be1;
    LOADP(A00, A01, A10, A11, Ae0, Ae1, 0)
    LOADP(B00, B01, B10, B11, Be0, Be1, 1)

    // descending compare-exchange: max to first operand
#define CE(A,B) { const unsigned mx_ = umx(A, B), mn_ = umn(A, B); \
                  A = mx_; B = mn_; }

#define SUBITER(P0,P1,P2,P3,E0,E1,TT,TP) { \
        const bf16x8 c00_ = P0, c01_ = P1, c10_ = P2, c11_ = P3; \
        const f32x4  ce0_ = E0, ce1_ = E1; \
        LOADP(P0, P1, P2, P3, E0, E1, (TP) & 31) \
        f32x4 acc0_ = __builtin_amdgcn_mfma_f32_16x16x32_bf16(c00_, b0, ce0_, 0, 0, 0); \
        acc0_       = __builtin_amdgcn_mfma_f32_16x16x32_bf16(c01_, b1, acc0_, 0, 0, 0); \
        f32x4 acc1_ = __builtin_amdgcn_mfma_f32_16x16x32_bf16(c10_, b0, ce1_, 0, 0, 0); \
        acc1_       = __builtin_amdgcn_mfma_f32_16x16x32_bf16(c11_, b1, acc1_, 0, 0, 0); \
        const unsigned tb_ = (unsigned)((TT) << 3); \
        unsigned k0 = (__float_as_uint(acc0_[0]) & 0xFFFFFF00u) | (tb_ + 0u); \
        unsigned k1 = (__float_as_uint(acc0_[1]) & 0xFFFFFF00u) | (tb_ + 1u); \
        unsigned k2 = (__float_as_uint(acc0_[2]) & 0xFFFFFF00u) | (tb_ + 2u); \
        unsigned k3 = (__float_as_uint(acc0_[3]) & 0xFFFFFF00u) | (tb_ + 3u); \
        unsigned k4 = (__float_as_uint(acc1_[0]) & 0xFFFFFF00u) | (tb_ + 4u); \
        unsigned k5 = (__float_as_uint(acc1_[1]) & 0xFFFFFF00u) | (tb_ + 5u); \
        unsigned k6 = (__float_as_uint(acc1_[2]) & 0xFFFFFF00u) | (tb_ + 6u); \
        unsigned k7 = (__float_as_uint(acc1_[3]) & 0xFFFFFF00u) | (tb_ + 7u); \
        /* Batcher odd-even mergesort, 8 keys, descending (19 CE) */ \
        CE(k0,k1) CE(k2,k3) CE(k4,k5) CE(k6,k7) \
        CE(k0,k2) CE(k1,k3) CE(k4,k6) CE(k5,k7) \
        CE(k1,k2) CE(k5,k6) \
        CE(k0,k4) CE(k1,k5) CE(k2,k6) CE(k3,k7) \
        CE(k2,k4) CE(k3,k5) \
        CE(k1,k2) CE(k3,k4) CE(k5,k6) \
        if (k0 > l11) { \
            /* half-cleaner pairing: l := top-12 multiset, l bitonic */ \
            CE(l11,k0) CE(l10,k1) CE(l9,k2) CE(l8,k3) \
            CE(l7,k4)  CE(l6,k5)  CE(l5,k6) CE(l4,k7) \
            /* bitonic-12 resort, descending */ \
            CE(l0,l6) CE(l1,l7) CE(l2,l8) CE(l3,l9) CE(l4,l10) CE(l5,l11) \
            CE(l0,l3) CE(l1,l4) CE(l2,l5) CE(l6,l9) CE(l7,l10) CE(l8,l11) \
            CE(l0,l1) CE(l0,l2) CE(l1,l2)  CE(l3,l4) CE(l3,l5) CE(l4,l5) \
            CE(l6,l7) CE(l6,l8) CE(l7,l8)  CE(l9,l10) CE(l9,l11) CE(l10,l11) \
        } }

    for (int t = 0; t < 32; t += 2) {
        SUBITER(A00, A01, A10, A11, Ae0, Ae1, t,     t + 2)
        SUBITER(B00, B01, B10, B11, Be0, Be1, t + 1, t + 3)
    }
#undef SUBITER
#undef CE
#undef LOADP

    // dump keys to LDS: slot = w*48 + q*12 + k  (0..191)
    {
        unsigned* kr = &keysh[rsub][w * 48 + q * 12];
        kr[0]=l0; kr[1]=l1; kr[2]=l2;  kr[3]=l3;
        kr[4]=l4; kr[5]=l5; kr[6]=l6;  kr[7]=l7;
        kr[8]=l8; kr[9]=l9; kr[10]=l10; kr[11]=l11;
    }
    __syncthreads();

    // per-row key-top-16 over 192 keys via ballot binary search.
    for (int rr = 0; rr < 4; ++rr) {
        const int lr = 4 * w + rr;
        const unsigned ka = keysh[lr][lane];
        const unsigned kb = keysh[lr][lane + 64];
        const unsigned kc = keysh[lr][lane + 128];

        unsigned tau = 0u;
#pragma unroll
        for (int b = 31; b >= 0; --b) {
            const unsigned t2 = tau | (1u << b);
            const int cnt = __popcll(__ballot(ka >= t2))
                          + __popcll(__ballot(kb >= t2))
                          + __popcll(__ballot(kc >= t2));
            if (cnt >= 16) tau = t2;
        }

        const unsigned long long m0 = __ballot(ka >= tau);
        const unsigned long long m1 = __ballot(kb >= tau);
        const unsigned long long m2 = __ballot(kc >= tau);
        const unsigned long long below = (lane == 0) ? 0ull
                                        : (~0ull >> (64 - lane));
        const int c0 = __popcll(m0);
        const int c1 = __popcll(m1);
        const int p0 = __popcll(m0 & below);
        const int p1 = c0 + __popcll(m1 & below);
        const int p2 = c0 + c1 + __popcll(m2 & below);

        unsigned short* outp =
            cand32 + (size_t)(row0 + lr) * 32 + blockIdx.y * 16;

#define EMIT(KX, SLOT, POS) \
        if ((KX) >= tau && (POS) < 16) { \
            const unsigned slot_ = (unsigned)(SLOT); \
            const unsigned idx_  = (KX) & 0xFFu; \
            const unsigned wq_   = slot_ / 48u; \
            const unsigned qq_   = (slot_ % 48u) / 12u; \
            const unsigned code_ = (unsigned)half0 + wq_ * 1024u \
                                 + ((idx_ >> 3) << 5) + (((idx_ >> 2) & 1u) << 4) \
                                 + (qq_ << 2) + (idx_ & 3u); \
            outp[POS] = (unsigned short)code_; \
        }
        EMIT(ka, lane,       p0)
        EMIT(kb, lane + 64,  p1)
        EMIT(kc, lane + 128, p2)
#undef EMIT
    }
}

// ---------------------------------------------------------------------------
// Kernel 2: fp64 re-rank of the 32 candidates (both gathers hoisted, one
// latency exposure), rank-based stable (d,idx) selection + Gumbel argmax
// (identical math to r15), outputs, scattered-bin histogram atomics,
// line-padded staging partials, and FUSED scalar epilogue in the last block
// (device-scope done-counter; atomic reads for cross-XCD coherence).
// ---------------------------------------------------------------------------
__global__ __launch_bounds__(256) void vq_finalize(const float* __restrict__ inp,
                                                   const float* __restrict__ cb,
                                                   const double* __restrict__ e2d,
                                                   const float* __restrict__ gumbel,
                                                   const unsigned short* __restrict__ cand32,
                                                   float* __restrict__ out,
                                                   int* __restrict__ hist,
                                                   double* __restrict__ lp64,
                                                   int* __restrict__ nv64,
                                                   int* __restrict__ done) {
    __shared__ double dvs[4][32];
    __shared__ int    dis[4][32];
    __shared__ double wl[4];
    __shared__ int    wv[4];
    __shared__ double red[256];
    __shared__ double s_nv;
    __shared__ int    s_last;

    const int tid  = threadIdx.x;
    const int w    = tid >> 6;
    const int lane = tid & 63;
    const int row  = blockIdx.x * 4 + w;
    const int g    = lane >> 2;   // quad id 0..15
    const int lq   = lane & 3;    // quarter within quad

    const float xf = inp[(size_t)row * EMB_DIM + lane];
    const double xd = (double)xf;

    // hoisted candidate ids + gathers + e2d (one latency exposure)
    const int code0 = (int)cand32[(size_t)row * 32 + g];
    const int code1 = (int)cand32[(size_t)row * 32 + 16 + g];
    const float4* ep0 = (const float4*)(cb + ((size_t)code0 << 6) + (lq << 4));
    const float4* ep1 = (const float4*)(cb + ((size_t)code1 << 6) + (lq << 4));
    const float4 a0 = ep0[0], a1 = ep0[1], a2 = ep0[2], a3 = ep0[3];
    const float4 b0 = ep1[0], b1 = ep1[1], b2 = ep1[2], b3 = ep1[3];
    const double ed0 = e2d[code0];
    const double ed1 = e2d[code1];

    // wave-wide ||x||^2 in fp64
    double x2 = xd * xd;
#pragma unroll
    for (int off = 32; off >= 1; off >>= 1) x2 += __shfl_xor(x2, off);
    const bool valid = sqrt(x2) > 1e-6;

    // lane's fp64 x-slice: dims [lq*16, lq*16+16) in registers
    double xq[16];
    {
        const float4* xp = (const float4*)(inp + (size_t)row * EMB_DIM + (lq << 4));
#pragma unroll
        for (int i = 0; i < 4; ++i) {
            const float4 v = xp[i];
            xq[4 * i + 0] = (double)v.x; xq[4 * i + 1] = (double)v.y;
            xq[4 * i + 2] = (double)v.z; xq[4 * i + 3] = (double)v.w;
        }
    }

#define DOT16(V0,V1,V2,V3, EDV, J) { \
        double d0_ = 0.0, d1_ = 0.0; \
        d0_ = fma(xq[0],  (double)V0.x, d0_);  d0_ = fma(xq[1],  (double)V0.y, d0_); \
        d0_ = fma(xq[2],  (double)V0.z, d0_);  d0_ = fma(xq[3],  (double)V0.w, d0_); \
        d0_ = fma(xq[4],  (double)V1.x, d0_);  d0_ = fma(xq[5],  (double)V1.y, d0_); \
        d0_ = fma(xq[6],  (double)V1.z, d0_);  d0_ = fma(xq[7],  (double)V1.w, d0_); \
        d1_ = fma(xq[8],  (double)V2.x, d1_);  d1_ = fma(xq[9],  (double)V2.y, d1_); \
        d1_ = fma(xq[10], (double)V2.z, d1_);  d1_ = fma(xq[11], (double)V2.w, d1_); \
        d1_ = fma(xq[12], (double)V3.x, d1_);  d1_ = fma(xq[13], (double)V3.y, d1_); \
        d1_ = fma(xq[14], (double)V3.z, d1_);  d1_ = fma(xq[15], (double)V3.w, d1_); \
        double dot_ = d0_ + d1_; \
        dot_ += __shfl_xor(dot_, 1); \
        dot_ += __shfl_xor(dot_, 2); \
        if (lq == 0) { \
            dvs[w][J] = x2 + (EDV) - 2.0 * dot_; \
            dis[w][J] = (J) < 16 ? code0 : code1; \
        } }

    DOT16(a0, a1, a2, a3, ed0, g)
    DOT16(b0, b1, b2, b3, ed1, 16 + g)
#undef DOT16
    __syncthreads();

    // one candidate per lane (lane<32). Rank by (d, idx) — exact stable order.
    const bool has = (lane < 32);
    double cd = has ? dvs[w][lane] : 1.0e300;
    int    ci = has ? dis[w][lane] : 0x7fffffff;

    int rank = 0;
#pragma unroll
    for (int off = 1; off < 32; ++off) {
        const double od = __shfl_xor(cd, off);   // stays within 0..31 group
        const int    oi = __shfl_xor(ci, off);
        if (od < cd || (od == cd && oi < ci)) ++rank;
    }

    // lanes with rank<10 (and holding a candidate) join the Gumbel race
    float sc = -3.0e38f;
    if (has && rank < TOP_K)
        sc = (float)(-cd) + gumbel[(size_t)row * TOP_K + rank];

    // wave argmax of (sc, tie -> smaller rank) carrying (cd, ci)
    double bd = cd; int bi = ci; int brk = rank;
#pragma unroll
    for (int off = 1; off < 64; off <<= 1) {
        const float  os = __shfl_xor(sc, off);
        const double od = __shfl_xor(bd, off);
        const int    oi = __shfl_xor(bi, off);
        const int    ork = __shfl_xor(brk, off);
        if (os > sc || (os == sc && ork < brk)) {
            sc = os; bd = od; bi = oi; brk = ork;
        }
    }
    const int   cidx = bi;            // uniform across wave
    const float mind = (float)bd;

    const float vm = valid ? 1.0f : 0.0f;
    const float qv = cb[(size_t)cidx * EMB_DIM + lane];
    out[QST_OFF + (size_t)row * EMB_DIM + lane] = xf + (qv * vm - xf);

    // loss term uses UNMASKED q_valid, masked by vm
    const double dq = (double)qv - xd;
    double l = dq * dq * (double)vm;
#pragma unroll
    for (int off = 32; off >= 1; off >>= 1) l += __shfl_xor(l, off);

    if (lane == 0) {
        wl[w] = l;
        wv[w] = valid ? 1 : 0;
        if (valid) atomicAdd(&hist[cidx], 1);   // scattered bins, low contention
        out[IDX_OFF + row]  = valid ? (float)cidx : 0.0f;
        out[MIND_OFF + row] = valid ? mind : 0.0f;
    }
    __syncthreads();   // also drains the hist atomics (barrier waitcnt)

    if (tid == 0) {
        const int slot = (int)(blockIdx.x & 63);
        atomicAdd(&lp64[slot * 8], wl[0] + wl[1] + wl[2] + wl[3]);
        atomicAdd(&nv64[slot * 16], wv[0] + wv[1] + wv[2] + wv[3]);
        __threadfence();
        const int old = atomicAdd(done, 1);
        s_last = (old == (int)gridDim.x - 1) ? 1 : 0;
    }
    __syncthreads();

    if (s_last) {
        // ---- fused scalar epilogue (runs once, in the last block) ----
        double lsum = 0.0; int nvl = 0;
        if (tid < 64) {
            lsum = atomicAdd(&lp64[tid * 8], 0.0);   // device-scope atomic read
            nvl  = atomicAdd(&nv64[tid * 16], 0);
        }
        red[tid] = lsum;
        __syncthreads();
        for (int s = 128; s >= 1; s >>= 1) {
            if (tid < s) red[tid] += red[tid + s];
            __syncthreads();
        }
        const double losstot = red[0];
        __syncthreads();

        red[tid] = (double)nvl;
        __syncthreads();
        for (int s = 128; s >= 1; s >>= 1) {
            if (tid < s) red[tid] += red[tid + s];
            __syncthreads();
        }
        if (tid == 0) s_nv = (red[0] > 0.5) ? red[0] : 1.0;
        __syncthreads();
        const double nv = s_nv;
        __syncthreads();

        double h = 0.0;
        for (int k = tid; k < NUM_EMB; k += 256) {
            const int c = atomicAdd(&hist[k], 0);    // device-scope atomic read
            const double p = (double)c / nv;
            h += p * log(p + 1e-10);
        }
        red[tid] = h;
        __syncthreads();
        for (int s = 128; s >= 1; s >>= 1) {
            if (tid < s) red[tid] += red[tid + s];
            __syncthreads();
        }
        if (tid == 0) {
            const double H = red[0];                 // sum p*log(p+1e-10)
            const double perp = exp(-H);
            const double ploss = -log(perp + 1e-10);
            const double lvq = losstot / (nv * (double)EMB_DIM);
            out[LOSS_OFF] = (float)(lvq + PERP_W * ploss);
            out[PERP_OFF] = (float)perp;
        }
    }
}

// ---------------------------------------------------------------------------
extern "C" void kernel_launch(void* const* d_in, const int* in_sizes, int n_in,
                              void* d_out, int out_size, void* d_ws, size_t ws_size,
                              hipStream_t stream) {
    const float* inp    = (const float*)d_in[0];  // [16384, 64]
    const float* cb     = (const float*)d_in[1];  // [8192, 64]
    const float* gumbel = (const float*)d_in[2];  // [16384, 10]
    float* out = (float*)d_out;

    char* ws = (char*)d_ws;
    float*          e2c    = (float*)(ws + WS_E2C);
    double*         e2d    = (double*)(ws + WS_E2D);
    unsigned short* cbs    = (unsigned short*)(ws + WS_CBS);
    int*            hist   = (int*)(ws + WS_HIST);
    double*         lp64   = (double*)(ws + WS_LP64);
    int*            nv64   = (int*)(ws + WS_NV64);
    int*            done   = (int*)(ws + WS_DONE);
    unsigned short* cand32 = (unsigned short*)(ws + WS_C32);

    vq_prep<<<NUM_EMB * 4 / 256, 256, 0, stream>>>(cb, e2c, e2d, cbs, hist,
                                                   lp64, nv64, done);
    vq_gemm_topk<<<dim3(N_ROWS / 16, 2), 256, 0, stream>>>(inp, cbs, e2c, cand32);
    vq_finalize<<<N_ROWS / 4, 256, 0, stream>>>(inp, cb, e2d, gumbel, cand32, out,
                                                hist, lp64, nv64, done);
}

// Round 17
// 184.232 us; speedup vs baseline: 1.4783x; 1.4783x over previous
//
#include <hip/hip_runtime.h>
#include <hip/hip_bf16.h>

// Problem constants
#define N_ROWS   16384      // 8*2048
#define EMB_DIM  64
#define NUM_EMB  8192
#define TOP_K    10
#define PERP_W   0.01

// Pass-1 (unchanged from r14/r15, absmax 0.0): grid (1024, 2); block = 256 thr
// = 4 waves = 16 rows x 4096 codes. Swizzled bf16 codebook -> fully coalesced
// A-loads. Per-lane register top-12 (packed u32 key), ballot key-top-16 per
// row per half -> 32 candidates/row. fp64 re-rank restores exact (d,idx).
// r17 = r15 graph (separate scalars kernel, NO fused epilogue/fences) +
// r16's safe wins (4-thread/code prep, hoisted finalize gathers).
#define M_CHUNK   12

// Output layout (all float32, concatenated in return order)
#define QST_OFF   0
#define LOSS_OFF  (N_ROWS * EMB_DIM)                 // 1048576
#define IDX_OFF   (LOSS_OFF + 1)                     // 1048577
#define MIND_OFF  (IDX_OFF + N_ROWS)                 // 1064961
#define PERP_OFF  (MIND_OFF + N_ROWS)                // 1081345

// ws layout (bytes)
#define WS_E2C    0                                  // 8192 f32 = 512-||e||^2/2 (32 KB)
#define WS_E2D    32768                              // 8192 f64   (64 KB)
#define WS_CBS    98304                              // swizzled bf16 codebook (1 MB)
#define WS_HIST   1146880                            // 8192 i32  (32 KB)
#define WS_LOSSP  1179648                            // 4096 f64  (32 KB)
#define WS_NVP    1212416                            // 4096 i32  (16 KB)
#define WS_C32    1228800                            // 16384*32 u16 (1 MB)

typedef short bf16x8 __attribute__((ext_vector_type(8)));
typedef float f32x4  __attribute__((ext_vector_type(4)));

__device__ __forceinline__ unsigned umx(unsigned a, unsigned b) {
    return __builtin_elementwise_max(a, b);
}
__device__ __forceinline__ unsigned umn(unsigned a, unsigned b) {
    return __builtin_elementwise_min(a, b);
}

__device__ __forceinline__ unsigned short f2bf(float f) {
    // round-to-nearest-even fp32 -> bf16 (inputs are finite gaussians)
    unsigned int u = __float_as_uint(f);
    unsigned int r = u + 0x7fffu + ((u >> 16) & 1u);
    return (unsigned short)(r >> 16);
}

// ---------------------------------------------------------------------------
// Kernel 0: prep — 4 threads per code (128 blocks): quad shuffle-reduce for
// ||e||^2 (fp32 + fp64), bf16 swizzled stores (byte-identical layout to r15),
// zero histogram.
// ---------------------------------------------------------------------------
__global__ __launch_bounds__(256) void vq_prep(const float* __restrict__ cb,
                                               float* __restrict__ e2c,
                                               double* __restrict__ e2d,
                                               unsigned short* __restrict__ cbs,
                                               int* __restrict__ hist) {
    const int g  = blockIdx.x * 256 + threadIdx.x;   // 0..32767
    const int k  = g >> 2;                           // code 0..8191
    const int lq = g & 3;                            // dim quarter

    if (g < NUM_EMB) hist[g] = 0;

    const float4* rp = (const float4*)(cb + (size_t)k * EMB_DIM + lq * 16);
    float  s  = 0.0f;
    double sd = 0.0;
    unsigned pk[8];
#pragma unroll
    for (int i = 0; i < 4; ++i) {
        const float4 v = rp[i];
        s  += v.x * v.x + v.y * v.y + v.z * v.z + v.w * v.w;
        sd += (double)v.x * (double)v.x + (double)v.y * (double)v.y
            + (double)v.z * (double)v.z + (double)v.w * (double)v.w;
        pk[2 * i + 0] = (unsigned)f2bf(v.x) | ((unsigned)f2bf(v.y) << 16);
        pk[2 * i + 1] = (unsigned)f2bf(v.z) | ((unsigned)f2bf(v.w) << 16);
    }
    // quad reduce (xor 1,2 stays inside the quad)
    s  += __shfl_xor(s, 1);  s  += __shfl_xor(s, 2);
    sd += __shfl_xor(sd, 1); sd += __shfl_xor(sd, 2);
    if (lq == 0) { e2c[k] = 512.0f - 0.5f * s; e2d[k] = sd; }

    // swizzled store: this thread owns 2 of the code's 8 16B chunks
    const int tp = k >> 5, r32 = k & 31, rsub = r32 & 15;
    unsigned short* basep = cbs + ((size_t)tp << 11)
                          + ((unsigned)(r32 & 16) << 6)
                          + (rsub << 3);
    const int hi  = lq >> 1;          // 0 = lo half (dims 0..31), 1 = hi half
    const int q2s = (lq & 1) * 2;     // starting q2 within half
    uint4 c0, c1;
    c0.x = pk[0]; c0.y = pk[1]; c0.z = pk[2]; c0.w = pk[3];
    c1.x = pk[4]; c1.y = pk[5]; c1.z = pk[6]; c1.w = pk[7];
    *(uint4*)(basep + hi * 512 + (q2s + 0) * 128) = c0;
    *(uint4*)(basep + hi * 512 + (q2s + 1) * 128) = c1;
}

// ---------------------------------------------------------------------------
// Kernel 1: MFMA distance GEMM + per-lane register top-12 + per-half per-row
// key-top-16 via ballot binary search. (byte-identical to r15, 90 us)
// ---------------------------------------------------------------------------
__global__ __launch_bounds__(256) void vq_gemm_topk(
        const float* __restrict__ inp, const unsigned short* __restrict__ cbs,
        const float* __restrict__ e2c, unsigned short* __restrict__ cand32) {
    __shared__ unsigned keysh[16][193];   // [row][slot 0..191], pad 193

    const int tid   = threadIdx.x;
    const int w     = tid >> 6;        // wave chunk 0..3
    const int lane  = tid & 63;
    const int q     = lane >> 4;       // quad: k-slice for A/B, code subgroup for D
    const int rsub  = lane & 15;
    const int row0  = blockIdx.x * 16;
    const int row   = row0 + rsub;
    const int half0 = blockIdx.y * 4096;
    const int cbase = half0 + w * 1024;
    const int tpbase = cbase >> 5;     // tile-pair base index

    const int eoff = q << 2;           // e2 lane offset (floats)

    // B fragments (this lane's row, k = q*8+j and +32), fp32 -> bf16
    bf16x8 b0, b1;
    {
        const float* xp = inp + (size_t)row * EMB_DIM + q * 8;
#pragma unroll
        for (int j = 0; j < 8; ++j) b0[j] = (short)f2bf(xp[j]);
#pragma unroll
        for (int j = 0; j < 8; ++j) b1[j] = (short)f2bf(xp[32 + j]);
    }

    // sorted-desc register list of packed (score|idx8); l0 best, l11 worst
    unsigned l0=0,l1=0,l2=0,l3=0,l4=0,l5=0,l6=0,l7=0,l8=0,l9=0,l10=0,l11=0;

    // fully-coalesced loads: base is wave-uniform, lane offset = lane*16B
#define LOADP(P0,P1,P2,P3,E0,E1,TT) { \
        const bf16x8* bp_ = ((const bf16x8*)cbs) + (size_t)(tpbase + (TT)) * 256; \
        P0 = bp_[lane];        P1 = bp_[lane + 64]; \
        P2 = bp_[lane + 128];  P3 = bp_[lane + 192]; \
        const float* ep_ = e2c + cbase + (TT) * 32; \
        E0 = *(const f32x4*)(ep_ + eoff); \
        E1 = *(const f32x4*)(ep_ + eoff + 16); }

    bf16x8 A00, A01, A10, A11, B00, B01, B10, B11;
    f32x4  Ae0, Ae1, Be0, Be1;
    LOADP(A00, A01, A10, A11, Ae0, Ae1, 0)
    LOADP(B00, B01, B10, B11, Be0, Be1, 1)

    // descending compare-exchange: max to first operand
#define CE(A,B) { const unsigned mx_ = umx(A, B), mn_ = umn(A, B); \
                  A = mx_; B = mn_; }

#define SUBITER(P0,P1,P2,P3,E0,E1,TT,TP) { \
        const bf16x8 c00_ = P0, c01_ = P1, c10_ = P2, c11_ = P3; \
        const f32x4  ce0_ = E0, ce1_ = E1; \
        LOADP(P0, P1, P2, P3, E0, E1, (TP) & 31) \
        f32x4 acc0_ = __builtin_amdgcn_mfma_f32_16x16x32_bf16(c00_, b0, ce0_, 0, 0, 0); \
        acc0_       = __builtin_amdgcn_mfma_f32_16x16x32_bf16(c01_, b1, acc0_, 0, 0, 0); \
        f32x4 acc1_ = __builtin_amdgcn_mfma_f32_16x16x32_bf16(c10_, b0, ce1_, 0, 0, 0); \
        acc1_       = __builtin_amdgcn_mfma_f32_16x16x32_bf16(c11_, b1, acc1_, 0, 0, 0); \
        const unsigned tb_ = (unsigned)((TT) << 3); \
        unsigned k0 = (__float_as_uint(acc0_[0]) & 0xFFFFFF00u) | (tb_ + 0u); \
        unsigned k1 = (__float_as_uint(acc0_[1]) & 0xFFFFFF00u) | (tb_ + 1u); \
        unsigned k2 = (__float_as_uint(acc0_[2]) & 0xFFFFFF00u) | (tb_ + 2u); \
        unsigned k3 = (__float_as_uint(acc0_[3]) & 0xFFFFFF00u) | (tb_ + 3u); \
        unsigned k4 = (__float_as_uint(acc1_[0]) & 0xFFFFFF00u) | (tb_ + 4u); \
        unsigned k5 = (__float_as_uint(acc1_[1]) & 0xFFFFFF00u) | (tb_ + 5u); \
        unsigned k6 = (__float_as_uint(acc1_[2]) & 0xFFFFFF00u) | (tb_ + 6u); \
        unsigned k7 = (__float_as_uint(acc1_[3]) & 0xFFFFFF00u) | (tb_ + 7u); \
        /* Batcher odd-even mergesort, 8 keys, descending (19 CE) */ \
        CE(k0,k1) CE(k2,k3) CE(k4,k5) CE(k6,k7) \
        CE(k0,k2) CE(k1,k3) CE(k4,k6) CE(k5,k7) \
        CE(k1,k2) CE(k5,k6) \
        CE(k0,k4) CE(k1,k5) CE(k2,k6) CE(k3,k7) \
        CE(k2,k4) CE(k3,k5) \
        CE(k1,k2) CE(k3,k4) CE(k5,k6) \
        if (k0 > l11) { \
            /* half-cleaner pairing: l := top-12 multiset, l bitonic */ \
            CE(l11,k0) CE(l10,k1) CE(l9,k2) CE(l8,k3) \
            CE(l7,k4)  CE(l6,k5)  CE(l5,k6) CE(l4,k7) \
            /* bitonic-12 resort, descending */ \
            CE(l0,l6) CE(l1,l7) CE(l2,l8) CE(l3,l9) CE(l4,l10) CE(l5,l11) \
            CE(l0,l3) CE(l1,l4) CE(l2,l5) CE(l6,l9) CE(l7,l10) CE(l8,l11) \
            CE(l0,l1) CE(l0,l2) CE(l1,l2)  CE(l3,l4) CE(l3,l5) CE(l4,l5) \
            CE(l6,l7) CE(l6,l8) CE(l7,l8)  CE(l9,l10) CE(l9,l11) CE(l10,l11) \
        } }

    for (int t = 0; t < 32; t += 2) {
        SUBITER(A00, A01, A10, A11, Ae0, Ae1, t,     t + 2)
        SUBITER(B00, B01, B10, B11, Be0, Be1, t + 1, t + 3)
    }
#undef SUBITER
#undef CE
#undef LOADP

    // dump keys to LDS: slot = w*48 + q*12 + k  (0..191)
    {
        unsigned* kr = &keysh[rsub][w * 48 + q * 12];
        kr[0]=l0; kr[1]=l1; kr[2]=l2;  kr[3]=l3;
        kr[4]=l4; kr[5]=l5; kr[6]=l6;  kr[7]=l7;
        kr[8]=l8; kr[9]=l9; kr[10]=l10; kr[11]=l11;
    }
    __syncthreads();

    // per-row key-top-16 over 192 keys via ballot binary search.
    for (int rr = 0; rr < 4; ++rr) {
        const int lr = 4 * w + rr;
        const unsigned ka = keysh[lr][lane];
        const unsigned kb = keysh[lr][lane + 64];
        const unsigned kc = keysh[lr][lane + 128];

        unsigned tau = 0u;
#pragma unroll
        for (int b = 31; b >= 0; --b) {
            const unsigned t2 = tau | (1u << b);
            const int cnt = __popcll(__ballot(ka >= t2))
                          + __popcll(__ballot(kb >= t2))
                          + __popcll(__ballot(kc >= t2));
            if (cnt >= 16) tau = t2;
        }

        const unsigned long long m0 = __ballot(ka >= tau);
        const unsigned long long m1 = __ballot(kb >= tau);
        const unsigned long long m2 = __ballot(kc >= tau);
        const unsigned long long below = (lane == 0) ? 0ull
                                        : (~0ull >> (64 - lane));
        const int c0 = __popcll(m0);
        const int c1 = __popcll(m1);
        const int p0 = __popcll(m0 & below);
        const int p1 = c0 + __popcll(m1 & below);
        const int p2 = c0 + c1 + __popcll(m2 & below);

        unsigned short* outp =
            cand32 + (size_t)(row0 + lr) * 32 + blockIdx.y * 16;

#define EMIT(KX, SLOT, POS) \
        if ((KX) >= tau && (POS) < 16) { \
            const unsigned slot_ = (unsigned)(SLOT); \
            const unsigned idx_  = (KX) & 0xFFu; \
            const unsigned wq_   = slot_ / 48u; \
            const unsigned qq_   = (slot_ % 48u) / 12u; \
            const unsigned code_ = (unsigned)half0 + wq_ * 1024u \
                                 + ((idx_ >> 3) << 5) + (((idx_ >> 2) & 1u) << 4) \
                                 + (qq_ << 2) + (idx_ & 3u); \
            outp[POS] = (unsigned short)code_; \
        }
        EMIT(ka, lane,       p0)
        EMIT(kb, lane + 64,  p1)
        EMIT(kc, lane + 128, p2)
#undef EMIT
    }
}

// ---------------------------------------------------------------------------
// Kernel 2: fp64 re-rank of the 32 candidates (both gathers + e2d hoisted,
// one latency exposure), rank-based stable (d,idx) selection + Gumbel argmax
// (identical math to r15), outputs, scattered-bin histogram atomics,
// per-block partial stores (NO fences, NO done-counter).
// ---------------------------------------------------------------------------
__global__ __launch_bounds__(256) void vq_finalize(const float* __restrict__ inp,
                                                   const float* __restrict__ cb,
                                                   const double* __restrict__ e2d,
                                                   const float* __restrict__ gumbel,
                                                   const unsigned short* __restrict__ cand32,
                                                   float* __restrict__ out,
                                                   int* __restrict__ hist,
                                                   double* __restrict__ lossp,
                                                   int* __restrict__ nvp) {
    __shared__ double dvs[4][32];
    __shared__ int    dis[4][32];
    __shared__ double wl[4];
    __shared__ int    wv[4];

    const int tid  = threadIdx.x;
    const int w    = tid >> 6;
    const int lane = tid & 63;
    const int row  = blockIdx.x * 4 + w;
    const int g    = lane >> 2;   // quad id 0..15
    const int lq   = lane & 3;    // quarter within quad

    const float xf = inp[(size_t)row * EMB_DIM + lane];
    const double xd = (double)xf;

    // hoisted candidate ids + gathers + e2d (one latency exposure)
    const int code0 = (int)cand32[(size_t)row * 32 + g];
    const int code1 = (int)cand32[(size_t)row * 32 + 16 + g];
    const float4* ep0 = (const float4*)(cb + ((size_t)code0 << 6) + (lq << 4));
    const float4* ep1 = (const float4*)(cb + ((size_t)code1 << 6) + (lq << 4));
    const float4 a0 = ep0[0], a1 = ep0[1], a2 = ep0[2], a3 = ep0[3];
    const float4 b0 = ep1[0], b1 = ep1[1], b2 = ep1[2], b3 = ep1[3];
    const double ed0 = e2d[code0];
    const double ed1 = e2d[code1];

    // wave-wide ||x||^2 in fp64
    double x2 = xd * xd;
#pragma unroll
    for (int off = 32; off >= 1; off >>= 1) x2 += __shfl_xor(x2, off);
    const bool valid = sqrt(x2) > 1e-6;

    // lane's fp64 x-slice: dims [lq*16, lq*16+16) in registers
    double xq[16];
    {
        const float4* xp = (const float4*)(inp + (size_t)row * EMB_DIM + (lq << 4));
#pragma unroll
        for (int i = 0; i < 4; ++i) {
            const float4 v = xp[i];
            xq[4 * i + 0] = (double)v.x; xq[4 * i + 1] = (double)v.y;
            xq[4 * i + 2] = (double)v.z; xq[4 * i + 3] = (double)v.w;
        }
    }

#define DOT16(V0,V1,V2,V3, EDV, J, CODE) { \
        double d0_ = 0.0, d1_ = 0.0; \
        d0_ = fma(xq[0],  (double)V0.x, d0_);  d0_ = fma(xq[1],  (double)V0.y, d0_); \
        d0_ = fma(xq[2],  (double)V0.z, d0_);  d0_ = fma(xq[3],  (double)V0.w, d0_); \
        d0_ = fma(xq[4],  (double)V1.x, d0_);  d0_ = fma(xq[5],  (double)V1.y, d0_); \
        d0_ = fma(xq[6],  (double)V1.z, d0_);  d0_ = fma(xq[7],  (double)V1.w, d0_); \
        d1_ = fma(xq[8],  (double)V2.x, d1_);  d1_ = fma(xq[9],  (double)V2.y, d1_); \
        d1_ = fma(xq[10], (double)V2.z, d1_);  d1_ = fma(xq[11], (double)V2.w, d1_); \
        d1_ = fma(xq[12], (double)V3.x, d1_);  d1_ = fma(xq[13], (double)V3.y, d1_); \
        d1_ = fma(xq[14], (double)V3.z, d1_);  d1_ = fma(xq[15], (double)V3.w, d1_); \
        double dot_ = d0_ + d1_; \
        dot_ += __shfl_xor(dot_, 1); \
        dot_ += __shfl_xor(dot_, 2); \
        if (lq == 0) { \
            dvs[w][J] = x2 + (EDV) - 2.0 * dot_; \
            dis[w][J] = (CODE); \
        } }

    DOT16(a0, a1, a2, a3, ed0, g,      code0)
    DOT16(b0, b1, b2, b3, ed1, 16 + g, code1)
#undef DOT16
    __syncthreads();

    // one candidate per lane (lane<32). Rank by (d, idx) — exact stable order.
    const bool has = (lane < 32);
    double cd = has ? dvs[w][lane] : 1.0e300;
    int    ci = has ? dis[w][lane] : 0x7fffffff;

    int rank = 0;
#pragma unroll
    for (int off = 1; off < 32; ++off) {
        const double od = __shfl_xor(cd, off);   // stays within 0..31 group
        const int    oi = __shfl_xor(ci, off);
        if (od < cd || (od == cd && oi < ci)) ++rank;
    }

    // lanes with rank<10 (and holding a candidate) join the Gumbel race
    float sc = -3.0e38f;
    if (has && rank < TOP_K)
        sc = (float)(-cd) + gumbel[(size_t)row * TOP_K + rank];

    // wave argmax of (sc, tie -> smaller rank) carrying (cd, ci)
    double bd = cd; int bi = ci; int brk = rank;
#pragma unroll
    for (int off = 1; off < 64; off <<= 1) {
        const float  os = __shfl_xor(sc, off);
        const double od = __shfl_xor(bd, off);
        const int    oi = __shfl_xor(bi, off);
        const int    ork = __shfl_xor(brk, off);
        if (os > sc || (os == sc && ork < brk)) {
            sc = os; bd = od; bi = oi; brk = ork;
        }
    }
    const int   cidx = bi;            // uniform across wave
    const float mind = (float)bd;

    const float vm = valid ? 1.0f : 0.0f;
    const float qv = cb[(size_t)cidx * EMB_DIM + lane];
    out[QST_OFF + (size_t)row * EMB_DIM + lane] = xf + (qv * vm - xf);

    // loss term uses UNMASKED q_valid, masked by vm
    const double dq = (double)qv - xd;
    double l = dq * dq * (double)vm;
#pragma unroll
    for (int off = 32; off >= 1; off >>= 1) l += __shfl_xor(l, off);

    if (lane == 0) {
        wl[w] = l;
        wv[w] = valid ? 1 : 0;
        if (valid) atomicAdd(&hist[cidx], 1);   // scattered bins, low contention
        out[IDX_OFF + row]  = valid ? (float)cidx : 0.0f;
        out[MIND_OFF + row] = valid ? mind : 0.0f;
    }
    __syncthreads();
    if (tid == 0) {
        lossp[blockIdx.x] = wl[0] + wl[1] + wl[2] + wl[3];
        nvp[blockIdx.x]   = wv[0] + wv[1] + wv[2] + wv[3];
    }
}

// ---------------------------------------------------------------------------
// Kernel 3: reduce per-block partials + histogram entropy -> scalars.
// Single block, 1024 threads (16 waves).
// ---------------------------------------------------------------------------
__global__ __launch_bounds__(1024) void vq_scalars(const double* __restrict__ lossp,
                                                   const int* __restrict__ nvp,
                                                   const int* __restrict__ hist,
                                                   float* __restrict__ out) {
    __shared__ double red[1024];
    __shared__ double s_nv;
    const int tid = threadIdx.x;

    double lsum = 0.0;
    int    nvl  = 0;
#pragma unroll
    for (int i = 0; i < 4; ++i) {
        const int j = tid + 1024 * i;   // 4096 partials
        lsum += lossp[j];
        nvl  += nvp[j];
    }

    red[tid] = lsum;
    __syncthreads();
    for (int s = 512; s >= 1; s >>= 1) {
        if (tid < s) red[tid] += red[tid + s];
        __syncthreads();
    }
    const double losstot = red[0];
    __syncthreads();

    red[tid] = (double)nvl;
    __syncthreads();
    for (int s = 512; s >= 1; s >>= 1) {
        if (tid < s) red[tid] += red[tid + s];
        __syncthreads();
    }
    if (tid == 0) s_nv = (red[0] > 0.5) ? red[0] : 1.0;
    __syncthreads();
    const double nv = s_nv;
    __syncthreads();

    double h = 0.0;
#pragma unroll
    for (int i = 0; i < 8; ++i) {
        const int k = tid + 1024 * i;   // 8192 bins
        const double p = (double)hist[k] / nv;
        h += p * log(p + 1e-10);
    }
    red[tid] = h;
    __syncthreads();
    for (int s = 512; s >= 1; s >>= 1) {
        if (tid < s) red[tid] += red[tid + s];
        __syncthreads();
    }
    if (tid == 0) {
        const double H = red[0];                 // sum p*log(p+1e-10)
        const double perp = exp(-H);
        const double ploss = -log(perp + 1e-10);
        const double lvq = losstot / (nv * (double)EMB_DIM);
        out[LOSS_OFF] = (float)(lvq + PERP_W * ploss);
        out[PERP_OFF] = (float)perp;
    }
}

// ---------------------------------------------------------------------------
extern "C" void kernel_launch(void* const* d_in, const int* in_sizes, int n_in,
                              void* d_out, int out_size, void* d_ws, size_t ws_size,
                              hipStream_t stream) {
    const float* inp    = (const float*)d_in[0];  // [16384, 64]
    const float* cb     = (const float*)d_in[1];  // [8192, 64]
    const float* gumbel = (const float*)d_in[2];  // [16384, 10]
    float* out = (float*)d_out;

    char* ws = (char*)d_ws;
    float*          e2c    = (float*)(ws + WS_E2C);
    double*         e2d    = (double*)(ws + WS_E2D);
    unsigned short* cbs    = (unsigned short*)(ws + WS_CBS);
    int*            hist   = (int*)(ws + WS_HIST);
    double*         lossp  = (double*)(ws + WS_LOSSP);
    int*            nvp    = (int*)(ws + WS_NVP);
    unsigned short* cand32 = (unsigned short*)(ws + WS_C32);

    vq_prep<<<NUM_EMB * 4 / 256, 256, 0, stream>>>(cb, e2c, e2d, cbs, hist);
    vq_gemm_topk<<<dim3(N_ROWS / 16, 2), 256, 0, stream>>>(inp, cbs, e2c, cand32);
    vq_finalize<<<N_ROWS / 4, 256, 0, stream>>>(inp, cb, e2d, gumbel, cand32, out,
                                                hist, lossp, nvp);
    vq_scalars<<<1, 1024, 0, stream>>>(lossp, nvp, hist, out);
}